// Round 2
// baseline (836.617 us; speedup 1.0000x reference)
//
#include <hip/hip_runtime.h>

typedef __attribute__((ext_vector_type(8))) short bf16x8;
typedef __attribute__((ext_vector_type(4))) float f32x4;

#define AS1 __attribute__((address_space(1)))
#define AS3 __attribute__((address_space(3)))

__device__ __forceinline__ void gload_lds16(const void* g, void* l) {
    __builtin_amdgcn_global_load_lds((const AS1 void*)(uintptr_t)g,
                                     (AS3 void*)(uintptr_t)l, 16, 0, 0);
}

// exact f32, no FMA contraction: 0.9*u + 2*i - s  (matches numpy op order)
__device__ __forceinline__ float u_new_exact(float u, float i, float s) {
    return __fsub_rn(__fadd_rn(__fmul_rn(0.9f, u), __fmul_rn(2.0f, i)), s);
}

__device__ __forceinline__ unsigned short f2bf_rne(float f) {
    unsigned int x = __float_as_uint(f);
    x += 0x7FFFu + ((x >> 16) & 1u);
    return (unsigned short)(x >> 16);
}

struct us4 { unsigned short x, y, z, w; };

// S2n = step(0.9*U2 + 2*I2 - S2), stored as bf16 {0,1} (exact)
__global__ void s2n_kernel(const float4* __restrict__ U2, const float4* __restrict__ I2,
                           const float4* __restrict__ S2, us4* __restrict__ s2n, int n4)
{
    int stride = gridDim.x * blockDim.x;
    for (int i = blockIdx.x * blockDim.x + threadIdx.x; i < n4; i += stride) {
        float4 u = U2[i], ii = I2[i], s = S2[i];
        us4 o;
        o.x = (u_new_exact(u.x, ii.x, s.x) > 0.f) ? (unsigned short)0x3F80 : (unsigned short)0;
        o.y = (u_new_exact(u.y, ii.y, s.y) > 0.f) ? (unsigned short)0x3F80 : (unsigned short)0;
        o.z = (u_new_exact(u.z, ii.z, s.z) > 0.f) ? (unsigned short)0x3F80 : (unsigned short)0;
        o.w = (u_new_exact(u.w, ii.w, s.w) > 0.f) ? (unsigned short)0x3F80 : (unsigned short)0;
        s2n[i] = o;
    }
}

// W3 fp32 -> bf16 (RNE)
__global__ void castw_kernel(const float4* __restrict__ W, us4* __restrict__ Wb, int n4)
{
    int stride = gridDim.x * blockDim.x;
    for (int i = blockIdx.x * blockDim.x + threadIdx.x; i < n4; i += stride) {
        float4 w = W[i];
        us4 o;
        o.x = f2bf_rne(w.x); o.y = f2bf_rne(w.y);
        o.z = f2bf_rne(w.z); o.w = f2bf_rne(w.w);
        Wb[i] = o;
    }
}

// C[M=4096][N=2048] = A[M][K=4096] @ Bw[N][K]^T, fused LIF epilogue.
// 128x128 tile, BK=64, 4 waves (2x2 of 64x64), 16x16x32 bf16 MFMA.
__global__ __launch_bounds__(256)
void lif_gemm_kernel(const unsigned short* __restrict__ A,   // s2n bf16 [M][K]
                     const unsigned short* __restrict__ Bw,  // W3 bf16 [N][K]
                     const float* __restrict__ b3,
                     const float* __restrict__ U3, const float* __restrict__ I3,
                     const float* __restrict__ S3,
                     float* __restrict__ outU, float* __restrict__ outI, float* __restrict__ outS)
{
    constexpr int N = 2048, K = 4096, BK = 64;
    __shared__ unsigned short sA[128 * BK];
    __shared__ unsigned short sB[128 * BK];

    const int tid  = threadIdx.x;
    const int wid  = tid >> 6;
    const int lane = tid & 63;
    const int wr = wid >> 1, wc = wid & 1;
    const int row0 = blockIdx.y * 128;
    const int col0 = blockIdx.x * 128;
    const int l15 = lane & 15;
    const int lk8 = (lane >> 4) * 8;

    f32x4 acc[4][4] = {};

    for (int kt = 0; kt < K; kt += BK) {
#pragma unroll
        for (int j = 0; j < 4; ++j) {
            int chunk = j * 256 + tid;
            int r = chunk >> 3;
            int c = (chunk & 7) * 8;
            const unsigned short* ga = A + (size_t)(row0 + r) * K + (kt + c);
            const unsigned short* gb = Bw + (size_t)(col0 + r) * K + (kt + c);
            char* la = (char*)sA + (size_t)(j * 256 + wid * 64) * 16;
            char* lb = (char*)sB + (size_t)(j * 256 + wid * 64) * 16;
            gload_lds16(ga, la);
            gload_lds16(gb, lb);
        }
        __syncthreads();
#pragma unroll
        for (int kk = 0; kk < BK / 32; ++kk) {
            bf16x8 af[4], bfr[4];
#pragma unroll
            for (int m = 0; m < 4; ++m)
                af[m] = *(const bf16x8*)&sA[(wr * 64 + m * 16 + l15) * BK + kk * 32 + lk8];
#pragma unroll
            for (int n = 0; n < 4; ++n)
                bfr[n] = *(const bf16x8*)&sB[(wc * 64 + n * 16 + l15) * BK + kk * 32 + lk8];
#pragma unroll
            for (int m = 0; m < 4; ++m)
#pragma unroll
                for (int n = 0; n < 4; ++n)
                    acc[m][n] = __builtin_amdgcn_mfma_f32_16x16x32_bf16(af[m], bfr[n], acc[m][n], 0, 0, 0);
        }
        __syncthreads();
    }

    // epilogue: U3n = 0.9*U3 + 2*I3 - S3 (exact); I3n = 0.85*I3 + 0.15*(mm + b3); S3n = step(U3n)
#pragma unroll
    for (int m = 0; m < 4; ++m) {
#pragma unroll
        for (int n = 0; n < 4; ++n) {
#pragma unroll
            for (int r = 0; r < 4; ++r) {
                int grow = row0 + wr * 64 + m * 16 + (lane >> 4) * 4 + r;
                int gcol = col0 + wc * 64 + n * 16 + l15;
                size_t off = (size_t)grow * N + gcol;
                float i3 = I3[off];
                float u3 = U3[off];
                float s3 = S3[off];
                float y = acc[m][n][r] + b3[gcol];
                float un = u_new_exact(u3, i3, s3);
                outU[off] = un;
                outI[off] = __fadd_rn(__fmul_rn(0.85f, i3), __fmul_rn(0.15f, y));
                outS[off] = (un > 0.f) ? 1.f : 0.f;
            }
        }
    }
}

extern "C" void kernel_launch(void* const* d_in, const int* in_sizes, int n_in,
                              void* d_out, int out_size, void* d_ws, size_t ws_size,
                              hipStream_t stream)
{
    const float* U2 = (const float*)d_in[17];
    const float* I2 = (const float*)d_in[18];
    const float* S2 = (const float*)d_in[19];
    const float* W3 = (const float*)d_in[20];
    const float* b3 = (const float*)d_in[21];
    const float* U3 = (const float*)d_in[22];
    const float* I3 = (const float*)d_in[23];
    const float* S3 = (const float*)d_in[24];

    unsigned short* s2n = (unsigned short*)d_ws;                              // 4096*4096 bf16 = 32 MB
    unsigned short* W3b = (unsigned short*)((char*)d_ws + (size_t)4096 * 4096 * 2); // 2048*4096 bf16 = 16 MB

    float* outU = (float*)d_out;
    float* outI = outU + (size_t)4096 * 2048;
    float* outS = outI + (size_t)4096 * 2048;

    s2n_kernel<<<2048, 256, 0, stream>>>((const float4*)U2, (const float4*)I2,
                                         (const float4*)S2, (us4*)s2n, 4096 * 4096 / 4);
    castw_kernel<<<2048, 256, 0, stream>>>((const float4*)W3, (us4*)W3b, 2048 * 4096 / 4);
    lif_gemm_kernel<<<dim3(2048 / 128, 4096 / 128), 256, 0, stream>>>(
        s2n, (const unsigned short*)W3b, b3, U3, I3, S3, outU, outI, outS);
}